// Round 3
// baseline (252.655 us; speedup 1.0000x reference)
//
#include <hip/hip_runtime.h>
#include <hip/hip_cooperative_groups.h>

namespace cg = cooperative_groups;

// B=2, T=512, C=256, HID=1024. ROWS=1024.
// Reference collapses (attn branch *0.0) to:
//   xp = x + bp;  h2 = LN(xp,g2,b2);  out = xp + relu(h2@W1.T+bf1)@W2.T + bf2
// Single cooperative kernel, 256 blocks x 256 threads (all co-resident):
//   phase0: LN (1 row/wave, 4 rows/block) -> h2 bf16; W1/W2 fp32->bf16
//           (8 floats/thread across the whole grid).   [full parallelism]
//   phase1: gemm1 tile (b>>4, b&15): H = relu(h2 @ w1b^T + bf1),
//           single K=256 pass, 64x64 tile.
//   phase2: gemm2 tile (b>>3, b&7): out = (x+bp) + H @ w2b^T + bf2,
//           32x32 tile, BK=512.
// grid.sync() replaces the two kernel-launch drains of the 3-kernel version.

typedef short bf8_t __attribute__((ext_vector_type(8)));        // 8 bf16 (MFMA operand)
typedef unsigned short us8_t __attribute__((ext_vector_type(8))); // 8 bf16 (store)
typedef float f4_t  __attribute__((ext_vector_type(4)));

__device__ inline unsigned short f2bf(float f) {  // round-to-nearest-even
  unsigned u = __float_as_uint(f);
  u += 0x7fffu + ((u >> 16) & 1u);
  return (unsigned short)(u >> 16);
}

__global__ __launch_bounds__(256) void fused_kernel(
    const float* __restrict__ x,  const float* __restrict__ bp,
    const float* __restrict__ g2, const float* __restrict__ b2,
    const float* __restrict__ W1, const float* __restrict__ bf1,
    const float* __restrict__ W2, const float* __restrict__ bf2,
    unsigned short* __restrict__ h2,  unsigned short* __restrict__ w1b,
    unsigned short* __restrict__ w2b, unsigned short* __restrict__ H,
    float* __restrict__ out) {
  // LDS reused across phases. Phase1: 2 x [64][264] ush (33792 B each).
  // Phase2: 2 x [32][520] ush (33280 B) aliased onto the same buffers.
  __shared__ unsigned short sA[64 * 264];
  __shared__ unsigned short sB[64 * 264];
  const int b = (int)blockIdx.x, tid = (int)threadIdx.x;
  const int wave = tid >> 6, lane = tid & 63;

  // ---------------- phase 0: LN + weight convert ----------------
  {
    // LN: one row per wave, rows 4b..4b+3. Lane holds 4 consecutive elems.
    const int row = (b << 2) + wave;
    const float4 xv  = *(const float4*)&x[(row << 8) + (lane << 2)];
    const float4 bp4 = *(const float4*)&bp[lane << 2];
    const float a0 = xv.x + bp4.x, a1 = xv.y + bp4.y;
    const float a2 = xv.z + bp4.z, a3 = xv.w + bp4.w;
    float s  = a0 + a1 + a2 + a3;
    float s2 = a0 * a0 + a1 * a1 + a2 * a2 + a3 * a3;
    #pragma unroll
    for (int off = 32; off > 0; off >>= 1) {
      s  += __shfl_xor(s, off);
      s2 += __shfl_xor(s2, off);
    }
    const float mu   = s * (1.0f / 256.0f);
    const float rstd = rsqrtf(s2 * (1.0f / 256.0f) - mu * mu + 1e-5f);
    const float4 g4 = *(const float4*)&g2[lane << 2];
    const float4 b4 = *(const float4*)&b2[lane << 2];
    ushort4 o;
    o.x = f2bf((a0 - mu) * rstd * g4.x + b4.x);
    o.y = f2bf((a1 - mu) * rstd * g4.y + b4.y);
    o.z = f2bf((a2 - mu) * rstd * g4.z + b4.z);
    o.w = f2bf((a3 - mu) * rstd * g4.w + b4.w);
    *(ushort4*)&h2[(row << 8) + (lane << 2)] = o;

    // Weight convert: 8 floats per thread, W1 then W2.
    const int e = ((b << 8) + tid) << 3;
    const float* src; unsigned short* dst;
    if (e < 262144) { src = W1 + e;            dst = w1b + e; }
    else            { src = W2 + (e - 262144); dst = w2b + (e - 262144); }
    const float4 v0 = *(const float4*)src;
    const float4 v1 = *(const float4*)(src + 4);
    us8_t o8;
    o8[0] = f2bf(v0.x); o8[1] = f2bf(v0.y); o8[2] = f2bf(v0.z); o8[3] = f2bf(v0.w);
    o8[4] = f2bf(v1.x); o8[5] = f2bf(v1.y); o8[6] = f2bf(v1.z); o8[7] = f2bf(v1.w);
    *(us8_t*)dst = o8;
  }

  __threadfence();
  cg::this_grid().sync();

  // ---------------- phase 1: gemm1 (64x64 tile, single K=256 pass) --------
  // H[1024][1024] = relu(h2[1024][256] @ w1b[1024][256]^T + bf1)
  {
    const int bm = (b >> 4) << 6, bn = (b & 15) << 6;
    const int wy = (wave >> 1) << 5, wx = (wave & 1) << 5;
    const int quad = lane >> 4, l16 = lane & 15;

    #pragma unroll
    for (int c = 0; c < 8; ++c) {
      const int ch = (c << 8) + tid;          // 2048 chunks of 8 bf16
      const int r = ch >> 5, cc = ch & 31;
      *(uint4*)&sA[r * 264 + (cc << 3)] =
          *(const uint4*)&h2[((bm + r) << 8) + (cc << 3)];
      *(uint4*)&sB[r * 264 + (cc << 3)] =
          *(const uint4*)&w1b[((bn + r) << 8) + (cc << 3)];
    }
    __syncthreads();

    f4_t acc[2][2] = {};
    #pragma unroll
    for (int ks = 0; ks < 8; ++ks) {
      bf8_t af[2], bv[2];
      #pragma unroll
      for (int i = 0; i < 2; ++i)
        af[i] = *(const bf8_t*)&sA[(wy + (i << 4) + l16) * 264 + (ks << 5) + (quad << 3)];
      #pragma unroll
      for (int j = 0; j < 2; ++j)
        bv[j] = *(const bf8_t*)&sB[(wx + (j << 4) + l16) * 264 + (ks << 5) + (quad << 3)];
      #pragma unroll
      for (int i = 0; i < 2; ++i)
        #pragma unroll
        for (int j = 0; j < 2; ++j)
          acc[i][j] = __builtin_amdgcn_mfma_f32_16x16x32_bf16(af[i], bv[j], acc[i][j], 0, 0, 0);
    }

    #pragma unroll
    for (int j = 0; j < 2; ++j) {
      const int n = bn + wx + (j << 4) + l16;
      const float bvv = bf1[n];
      #pragma unroll
      for (int i = 0; i < 2; ++i)
        #pragma unroll
        for (int r = 0; r < 4; ++r) {
          const int m = bm + wy + (i << 4) + (quad << 2) + r;
          H[(m << 10) + n] = f2bf(fmaxf(acc[i][j][r] + bvv, 0.0f));
        }
    }
  }

  __threadfence();
  cg::this_grid().sync();

  // ---------------- phase 2: gemm2 (32x32 tile, BK=512) -------------------
  // out[1024][256] = (x+bp) + H[1024][1024] @ w2b[256][1024]^T + bf2
  {
    const int bm = (b >> 3) << 5, bn = (b & 7) << 5;
    const int wy = (wave >> 1) << 4, wx = (wave & 1) << 4;
    const int quad = lane >> 4, l16 = lane & 15;
    f4_t acc = {};

    for (int kt = 0; kt < 1024; kt += 512) {
      #pragma unroll
      for (int c = 0; c < 8; ++c) {
        const int ch = (c << 8) + tid;        // 2048 chunks of 8 bf16
        const int r = ch >> 6, cc = ch & 63;
        *(uint4*)&sA[r * 520 + (cc << 3)] =
            *(const uint4*)&H[((bm + r) << 10) + kt + (cc << 3)];
        *(uint4*)&sB[r * 520 + (cc << 3)] =
            *(const uint4*)&w2b[((bn + r) << 10) + kt + (cc << 3)];
      }
      __syncthreads();
      #pragma unroll
      for (int ks = 0; ks < 16; ++ks) {
        const bf8_t af = *(const bf8_t*)&sA[(wy + l16) * 520 + (ks << 5) + (quad << 3)];
        const bf8_t bv = *(const bf8_t*)&sB[(wx + l16) * 520 + (ks << 5) + (quad << 3)];
        acc = __builtin_amdgcn_mfma_f32_16x16x32_bf16(af, bv, acc, 0, 0, 0);
      }
      __syncthreads();
    }

    const int n = bn + wx + l16;
    const float bvv = bf2[n];
    const float bpn = bp[n];
    #pragma unroll
    for (int r = 0; r < 4; ++r) {
      const int m = bm + wy + (quad << 2) + r;
      out[(m << 8) + n] = acc[r] + bvv + x[(m << 8) + n] + bpn;
    }
  }
}

extern "C" void kernel_launch(void* const* d_in, const int* in_sizes, int n_in,
                              void* d_out, int out_size, void* d_ws, size_t ws_size,
                              hipStream_t stream) {
  // inputs: x, Wt, Wp, bp, g1, b1, g2, b2, W1, bf1, W2, bf2
  const float* x   = (const float*)d_in[0];
  const float* bp  = (const float*)d_in[3];
  const float* g2  = (const float*)d_in[6];
  const float* b2  = (const float*)d_in[7];
  const float* W1  = (const float*)d_in[8];
  const float* bf1 = (const float*)d_in[9];
  const float* W2  = (const float*)d_in[10];
  const float* bf2 = (const float*)d_in[11];
  float* out = (float*)d_out;

  unsigned short* h2  = (unsigned short*)d_ws;   // 512 KB
  unsigned short* w1b = h2 + 262144;             // 512 KB
  unsigned short* w2b = w1b + 262144;            // 512 KB
  unsigned short* H   = w2b + 262144;            // 2 MB bf16 [1024][1024]

  void* args[] = {(void*)&x, (void*)&bp, (void*)&g2, (void*)&b2,
                  (void*)&W1, (void*)&bf1, (void*)&W2, (void*)&bf2,
                  (void*)&h2, (void*)&w1b, (void*)&w2b, (void*)&H, (void*)&out};
  hipLaunchCooperativeKernel((const void*)fused_kernel, dim3(256), dim3(256),
                             args, 0, stream);
}

// Round 4
// 118.404 us; speedup vs baseline: 2.1338x; 2.1338x over previous
//
#include <hip/hip_runtime.h>

// B=2, T=512, C=256, HID=1024. ROWS=1024.
// Reference collapses (attn branch *0.0) to:
//   xp = x + bp;  h2 = LN(xp,g2,b2);  out = xp + relu(h2@W1.T+bf1)@W2.T + bf2
// 3-kernel structure. Measured session facts:
//   - kernel-launch boundaries under graph capture are ~free (r0 vs r1/r2);
//   - cooperative grid.sync costs ~55 us EACH on gfx950 at 256 blocks (r3);
//   - fusing LN/convert into the GEMM critical path at 1 block/CU costs ~2 us (r1).
// So: prep at high parallelism, GEMMs read pre-converted bf16.
//   prep:  LN rows (1 row/wave) -> h2 bf16; W1/W2 fp32 -> bf16.
//   gemm1: H = relu(h2 @ w1b^T + bf1), single K=256 pass, 1 barrier.
//   gemm2: out = (x+bp) + H @ w2b^T + bf2, BK=512.

typedef short bf8_t __attribute__((ext_vector_type(8)));  // 8 bf16 (MFMA operand)
typedef float f4_t  __attribute__((ext_vector_type(4)));

__device__ inline unsigned short f2bf(float f) {  // round-to-nearest-even
  unsigned u = __float_as_uint(f);
  u += 0x7fffu + ((u >> 16) & 1u);
  return (unsigned short)(u >> 16);
}

// ---- prep: blocks [0,256) = LN (4 rows/block, 1 row/wave);
//            blocks [256,768) = W1/W2 -> bf16 (1024 floats/block) ----
__global__ __launch_bounds__(256) void prep_kernel(
    const float* __restrict__ x, const float* __restrict__ bp,
    const float* __restrict__ g2, const float* __restrict__ b2,
    const float* __restrict__ W1, const float* __restrict__ W2,
    unsigned short* __restrict__ h2,
    unsigned short* __restrict__ w1b, unsigned short* __restrict__ w2b) {
  const int b = (int)blockIdx.x, t = (int)threadIdx.x;
  const int wave = t >> 6, lane = t & 63;
  if (b < 256) {
    const int row = (b << 2) + wave;
    const float4 xv  = *(const float4*)&x[(row << 8) + (lane << 2)];
    const float4 bp4 = *(const float4*)&bp[lane << 2];
    const float a0 = xv.x + bp4.x, a1 = xv.y + bp4.y;
    const float a2 = xv.z + bp4.z, a3 = xv.w + bp4.w;
    float s  = a0 + a1 + a2 + a3;
    float s2 = a0 * a0 + a1 * a1 + a2 * a2 + a3 * a3;
    #pragma unroll
    for (int off = 32; off > 0; off >>= 1) {
      s  += __shfl_xor(s, off);
      s2 += __shfl_xor(s2, off);
    }
    const float mu   = s * (1.0f / 256.0f);
    const float rstd = rsqrtf(s2 * (1.0f / 256.0f) - mu * mu + 1e-5f);
    const float4 g4 = *(const float4*)&g2[lane << 2];
    const float4 b4 = *(const float4*)&b2[lane << 2];
    ushort4 o;
    o.x = f2bf((a0 - mu) * rstd * g4.x + b4.x);
    o.y = f2bf((a1 - mu) * rstd * g4.y + b4.y);
    o.z = f2bf((a2 - mu) * rstd * g4.z + b4.z);
    o.w = f2bf((a3 - mu) * rstd * g4.w + b4.w);
    *(ushort4*)&h2[(row << 8) + (lane << 2)] = o;
  } else {
    const int e = ((b - 256) << 10) + (t << 2);  // 4 floats per thread
    const float* src; unsigned short* dst;
    if (e < 262144) { src = W1 + e;            dst = w1b + e; }
    else            { src = W2 + (e - 262144); dst = w2b + (e - 262144); }
    const float4 v = *(const float4*)src;
    ushort4 o;
    o.x = f2bf(v.x); o.y = f2bf(v.y); o.z = f2bf(v.z); o.w = f2bf(v.w);
    *(ushort4*)dst = o;
  }
}

// ---- GEMM1: H[1024][1024] = relu(h2[1024][256] @ W1[1024][256]^T + bf1) ----
// 64x64 tile, single K=256 pass (1 barrier). 4 waves 2x2, wave=32x32 via
// 2x2 mfma_16x16x32 frags. LDS row stride 264 ush (528B = 4-bank shift/row):
// frag reads 2-way alias only (free).
__global__ __launch_bounds__(256) void gemm1_kernel(
    const unsigned short* __restrict__ A,   // h2, K-major [1024][256]
    const unsigned short* __restrict__ Bm,  // w1b, K-major [1024][256]
    const float* __restrict__ bias,         // bf1[1024]
    unsigned short* __restrict__ H) {       // [1024][1024] bf16
  __shared__ unsigned short As[64 * 264];
  __shared__ unsigned short Bs[64 * 264];
  const int tid = threadIdx.x;
  const int bm = (int)blockIdx.y << 6, bn = (int)blockIdx.x << 6;
  const int wave = tid >> 6, lane = tid & 63;
  const int wy = (wave >> 1) << 5, wx = (wave & 1) << 5;
  const int quad = lane >> 4, l16 = lane & 15;

  #pragma unroll
  for (int c = 0; c < 8; ++c) {
    const int ch = (c << 8) + tid;          // 2048 chunks of 8 bf16
    const int r = ch >> 5, cc = ch & 31;
    *(uint4*)&As[r * 264 + (cc << 3)] =
        *(const uint4*)&A[((bm + r) << 8) + (cc << 3)];
    *(uint4*)&Bs[r * 264 + (cc << 3)] =
        *(const uint4*)&Bm[((bn + r) << 8) + (cc << 3)];
  }
  __syncthreads();

  f4_t acc[2][2] = {};
  #pragma unroll
  for (int ks = 0; ks < 8; ++ks) {
    bf8_t af[2], bv[2];
    #pragma unroll
    for (int i = 0; i < 2; ++i)
      af[i] = *(const bf8_t*)&As[(wy + (i << 4) + l16) * 264 + (ks << 5) + (quad << 3)];
    #pragma unroll
    for (int j = 0; j < 2; ++j)
      bv[j] = *(const bf8_t*)&Bs[(wx + (j << 4) + l16) * 264 + (ks << 5) + (quad << 3)];
    #pragma unroll
    for (int i = 0; i < 2; ++i)
      #pragma unroll
      for (int j = 0; j < 2; ++j)
        acc[i][j] = __builtin_amdgcn_mfma_f32_16x16x32_bf16(af[i], bv[j], acc[i][j], 0, 0, 0);
  }

  #pragma unroll
  for (int j = 0; j < 2; ++j) {
    const int n = bn + wx + (j << 4) + l16;
    const float bvv = bias[n];
    #pragma unroll
    for (int i = 0; i < 2; ++i)
      #pragma unroll
      for (int r = 0; r < 4; ++r) {
        const int m = bm + wy + (i << 4) + (quad << 2) + r;
        H[(m << 10) + n] = f2bf(fmaxf(acc[i][j][r] + bvv, 0.0f));
      }
  }
}

// ---- GEMM2: out[1024][256] = (x+bp) + H[1024][1024] @ W2[256][1024]^T + bf2 ----
// 32x32 tile, BK=512 (2 K-iters). 4 waves 2x2, one 16x16 frag per wave.
__global__ __launch_bounds__(256) void gemm2_kernel(
    const unsigned short* __restrict__ A,   // H, K-major [1024][1024]
    const unsigned short* __restrict__ Bm,  // w2b, K-major [256][1024]
    const float* __restrict__ bf2,
    const float* __restrict__ x, const float* __restrict__ bp,
    float* __restrict__ out) {
  __shared__ unsigned short As[32 * 520];
  __shared__ unsigned short Bs[32 * 520];
  const int tid = threadIdx.x;
  const int bm = (int)blockIdx.y << 5, bn = (int)blockIdx.x << 5;
  const int wave = tid >> 6, lane = tid & 63;
  const int wy = (wave >> 1) << 4, wx = (wave & 1) << 4;
  const int quad = lane >> 4, l16 = lane & 15;
  f4_t acc = {};

  for (int kt = 0; kt < 1024; kt += 512) {
    #pragma unroll
    for (int c = 0; c < 8; ++c) {
      const int ch = (c << 8) + tid;        // 2048 chunks of 8 bf16
      const int r = ch >> 6, cc = ch & 63;
      *(uint4*)&As[r * 520 + (cc << 3)] =
          *(const uint4*)&A[((bm + r) << 10) + kt + (cc << 3)];
      *(uint4*)&Bs[r * 520 + (cc << 3)] =
          *(const uint4*)&Bm[((bn + r) << 10) + kt + (cc << 3)];
    }
    __syncthreads();
    #pragma unroll
    for (int ks = 0; ks < 16; ++ks) {
      const bf8_t af = *(const bf8_t*)&As[(wy + l16) * 520 + (ks << 5) + (quad << 3)];
      const bf8_t bv = *(const bf8_t*)&Bs[(wx + l16) * 520 + (ks << 5) + (quad << 3)];
      acc = __builtin_amdgcn_mfma_f32_16x16x32_bf16(af, bv, acc, 0, 0, 0);
    }
    __syncthreads();
  }

  const int n = bn + wx + l16;
  const float bvv = bf2[n];
  const float bpn = bp[n];
  #pragma unroll
  for (int r = 0; r < 4; ++r) {
    const int m = bm + wy + (quad << 2) + r;
    out[(m << 8) + n] = acc[r] + bvv + x[(m << 8) + n] + bpn;
  }
}

extern "C" void kernel_launch(void* const* d_in, const int* in_sizes, int n_in,
                              void* d_out, int out_size, void* d_ws, size_t ws_size,
                              hipStream_t stream) {
  // inputs: x, Wt, Wp, bp, g1, b1, g2, b2, W1, bf1, W2, bf2
  const float* x   = (const float*)d_in[0];
  const float* bp  = (const float*)d_in[3];
  const float* g2  = (const float*)d_in[6];
  const float* b2  = (const float*)d_in[7];
  const float* W1  = (const float*)d_in[8];
  const float* bf1 = (const float*)d_in[9];
  const float* W2  = (const float*)d_in[10];
  const float* bf2 = (const float*)d_in[11];
  float* out = (float*)d_out;

  unsigned short* h2  = (unsigned short*)d_ws;   // 512 KB
  unsigned short* w1b = h2 + 262144;             // 512 KB
  unsigned short* w2b = w1b + 262144;            // 512 KB
  unsigned short* H   = w2b + 262144;            // 2 MB bf16 [1024][1024]

  prep_kernel<<<768, 256, 0, stream>>>(x, bp, g2, b2, W1, W2, h2, w1b, w2b);
  gemm1_kernel<<<dim3(16, 16), 256, 0, stream>>>(h2, w1b, bf1, H);
  gemm2_kernel<<<dim3(8, 32), 256, 0, stream>>>(H, w2b, bf2, x, bp, out);
}